// Round 2
// baseline (15600.601 us; speedup 1.0000x reference)
//
#include <hip/hip_runtime.h>
#include <hip/hip_bf16.h>

#define NLAYER 3
#define EDIM   128
#define NHEAD  4
#define DHEAD  32
#define FFDIM  256
#define NCLS   4
#define SEQ    64
#define TDIM   1024

typedef unsigned short u16;

__device__ __forceinline__ float bf2f_raw(unsigned int u) {
    union { unsigned int i; float f; } c;
    c.i = (unsigned int)u << 16;
    return c.f;
}
__device__ __forceinline__ u16 f2bf_u(float f) {
    __hip_bfloat16 h = __float2bfloat16(f);
    union { __hip_bfloat16 h; u16 u; } c; c.h = h; return c.u;
}
// swizzled LDS layouts (no padding; 64KB exactly for 2 blocks/CU)
__device__ __forceinline__ int xsw(int s_, int e_) { return s_ * EDIM + ((e_ + s_) & (EDIM - 1)); }
__device__ __forceinline__ int hsw(int s_, int e_) { return s_ * EDIM + ((e_ + 2 * s_) & (EDIM - 1)); }

// 32 fp32 weights (one row chunk) FMA'd into 32 fp32 accumulators
__device__ __forceinline__ void fma_row32(const float* __restrict__ wrow, float hval, float* acc) {
    const float4* p = reinterpret_cast<const float4*>(wrow);
#pragma unroll
    for (int t = 0; t < 8; ++t) {
        const float4 u = p[t];
        acc[t*4+0] += hval * u.x;
        acc[t*4+1] += hval * u.y;
        acc[t*4+2] += hval * u.z;
        acc[t*4+3] += hval * u.w;
    }
}

// LayerNorm of xs -> bf16 dst; 4 threads per token
__device__ __forceinline__ void block_ln(const float* __restrict__ xsm, u16* __restrict__ dst,
                                         const float* __restrict__ gm, const float* __restrict__ bt,
                                         int tid) {
    const int ss = tid >> 2;
    const int gq = tid & 3;
    float vals[32];
    float sum = 0.f, sq = 0.f;
#pragma unroll
    for (int i = 0; i < 32; ++i) {
        float v = xsm[xsw(ss, gq * 32 + i)];
        vals[i] = v; sum += v; sq += v * v;
    }
    sum += __shfl_xor(sum, 1); sum += __shfl_xor(sum, 2);
    sq  += __shfl_xor(sq , 1); sq  += __shfl_xor(sq , 2);
    const float m = sum * (1.0f / 128.0f);
    const float var = sq * (1.0f / 128.0f) - m * m;
    const float r = rsqrtf(var + 1e-5f);
#pragma unroll
    for (int i = 0; i < 32; ++i) {
        const int e = gq * 32 + i;
        float o = (vals[i] - m) * r * gm[e] + bt[e];
        dst[hsw(ss, e)] = f2bf_u(o);
    }
}

__global__ void __launch_bounds__(256, 2)
row_former(const float* __restrict__ emb,  const float* __restrict__ cls,
           const float* __restrict__ ln1g, const float* __restrict__ ln1b,
           const float* __restrict__ wq,   const float* __restrict__ bq,
           const float* __restrict__ wk,   const float* __restrict__ bk,
           const float* __restrict__ wv,   const float* __restrict__ bv,
           const float* __restrict__ wo,   const float* __restrict__ bo,
           const float* __restrict__ ln2g, const float* __restrict__ ln2b,
           const float* __restrict__ w1,   const float* __restrict__ b1,
           const float* __restrict__ w2,   const float* __restrict__ b2,
           const float* __restrict__ olng, const float* __restrict__ olnb,
           const int* __restrict__ dvec,   float* __restrict__ out) {
    __shared__ float xs[SEQ * EDIM];   // residual stream, fp32, 32KB
    __shared__ u16   hs[SEQ * EDIM];   // bf16 scratch (LN out / attn out), 16KB
    __shared__ u16   ts[SEQ * EDIM];   // bf16 scratch (FFN chunk), 16KB

    const int n   = blockIdx.x;
    const int tid = threadIdx.x;
    const int s   = tid & 63;   // token index for matmul/attention phases
    const int hh  = tid >> 6;   // head / column-group index
    const int lim = dvec[n / TDIM] + NCLS;

    // ---- load x (cls tokens replace positions < C) ----
    {
        const float* src = emb + (size_t)n * (SEQ * EDIM);
#pragma unroll
        for (int r = 0; r < 8; ++r) {
            const int base = (tid + r * 256) * 4;    // element index, 4 floats/thread/round
            const int ss = base >> 7, e0 = base & 127;
            const float* p = (ss < NCLS) ? (cls + ss * EDIM + e0) : (src + base);
            const float4 u = *reinterpret_cast<const float4*>(p);
            xs[xsw(ss, e0 + 0)] = u.x;
            xs[xsw(ss, e0 + 1)] = u.y;
            xs[xsw(ss, e0 + 2)] = u.z;
            xs[xsw(ss, e0 + 3)] = u.w;
        }
    }
    __syncthreads();

    for (int l = 0; l < NLAYER; ++l) {
        // ---- LN1 -> hs ----
        block_ln(xs, hs, ln1g + l * EDIM, ln1b + l * EDIM, tid);
        __syncthreads();

        // ---- q,k,v projection: thread (hh,s) computes [s][hh*32..+32] ----
        float qv[DHEAD], kv[DHEAD], vv[DHEAD];
#pragma unroll
        for (int c = 0; c < DHEAD; ++c) { qv[c] = 0.f; kv[c] = 0.f; vv[c] = 0.f; }
        {
            const float* wqp = wq + (size_t)l * EDIM * EDIM + hh * DHEAD;
            const float* wkp = wk + (size_t)l * EDIM * EDIM + hh * DHEAD;
            const float* wvp = wv + (size_t)l * EDIM * EDIM + hh * DHEAD;
#pragma unroll 1
            for (int kk = 0; kk < EDIM; ++kk) {
                const float hval = bf2f_raw(hs[hsw(s, kk)]);
                fma_row32(wqp + kk * EDIM, hval, qv);
                fma_row32(wkp + kk * EDIM, hval, kv);
                fma_row32(wvp + kk * EDIM, hval, vv);
            }
        }
#pragma unroll
        for (int c = 0; c < DHEAD; ++c) {
            qv[c] += bq[l * EDIM + hh * DHEAD + c];
            kv[c] += bk[l * EDIM + hh * DHEAD + c];
            vv[c] += bv[l * EDIM + hh * DHEAD + c];
        }
        // ---- RoPE (pos = s, per-head dim c) ----
#pragma unroll
        for (int c = 0; c < 16; ++c) {
            const float inv = __expf((float)c * -0.71955784156f);  // ln(1e5)/16
            const float ang = (float)s * inv;
            float sn, cs;
            sincosf(ang, &sn, &cs);
            const float q1 = qv[c], q2 = qv[c + 16];
            qv[c]      = q1 * cs - q2 * sn;
            qv[c + 16] = q2 * cs + q1 * sn;
            const float k1 = kv[c], k2 = kv[c + 16];
            kv[c]      = k1 * cs - k2 * sn;
            kv[c + 16] = k2 * cs + k1 * sn;
        }

        // ---- attention: online softmax over 64 keys, k/v via wave shuffles ----
        float ov[DHEAD];
#pragma unroll
        for (int c = 0; c < DHEAD; ++c) ov[c] = 0.f;
        float mrun = -3.0e38f, lrun = 0.f;
#pragma unroll 1
        for (int j = 0; j < SEQ; ++j) {
            float dot = 0.f;
#pragma unroll
            for (int c = 0; c < DHEAD; ++c) dot += qv[c] * __shfl(kv[c], j);
            const float sc = dot * 0.17677669529663687f + ((j >= lim) ? -1.0e9f : 0.0f);
            const float mnew = fmaxf(mrun, sc);
            const float corr = __expf(mrun - mnew);
            const float p    = __expf(sc - mnew);
            lrun = lrun * corr + p;
#pragma unroll
            for (int c = 0; c < DHEAD; ++c) ov[c] = ov[c] * corr + p * __shfl(vv[c], j);
            mrun = mnew;
        }
        {
            const float rl = 1.0f / lrun;
#pragma unroll
            for (int c = 0; c < DHEAD; ++c) ov[c] *= rl;
        }
        __syncthreads();                 // all waves done reading hs (LN1 out)
#pragma unroll
        for (int c = 0; c < DHEAD; ++c)  // attn output -> hs
            hs[hsw(s, hh * DHEAD + c)] = f2bf_u(ov[c]);
        __syncthreads();

        // ---- out projection + residual ----
        float acc[DHEAD];
#pragma unroll
        for (int c = 0; c < DHEAD; ++c) acc[c] = 0.f;
        {
            const float* wop = wo + (size_t)l * EDIM * EDIM + hh * DHEAD;
#pragma unroll 2
            for (int kk = 0; kk < EDIM; ++kk) {
                const float hval = bf2f_raw(hs[hsw(s, kk)]);
                fma_row32(wop + kk * EDIM, hval, acc);
            }
        }
#pragma unroll
        for (int c = 0; c < DHEAD; ++c)
            xs[xsw(s, hh * DHEAD + c)] += acc[c] + bo[l * EDIM + hh * DHEAD + c];
        __syncthreads();

        // ---- LN2 -> hs ----
        block_ln(xs, hs, ln2g + l * EDIM, ln2b + l * EDIM, tid);
        __syncthreads();

        // ---- FFN in two 128-wide chunks ----
        float facc[DHEAD];
#pragma unroll
        for (int c = 0; c < DHEAD; ++c) facc[c] = 0.f;
#pragma unroll 1
        for (int ch = 0; ch < 2; ++ch) {
            float tacc[DHEAD];
#pragma unroll
            for (int c = 0; c < DHEAD; ++c) tacc[c] = 0.f;
            const float* w1p = w1 + (size_t)l * EDIM * FFDIM + ch * 128 + hh * DHEAD;
#pragma unroll 2
            for (int kk = 0; kk < EDIM; ++kk) {
                const float hval = bf2f_raw(hs[hsw(s, kk)]);
                fma_row32(w1p + kk * FFDIM, hval, tacc);
            }
            // bias + gelu(tanh approx, matching jax.nn.gelu) -> ts
#pragma unroll
            for (int c = 0; c < DHEAD; ++c) {
                const float y = tacc[c] + b1[l * FFDIM + ch * 128 + hh * DHEAD + c];
                const float t = tanhf(0.7978845608028654f * (y + 0.044715f * y * y * y));
                ts[hsw(s, hh * DHEAD + c)] = f2bf_u(0.5f * y * (1.0f + t));
            }
            __syncthreads();
            const float* w2p = w2 + ((size_t)l * FFDIM + ch * 128) * EDIM + hh * DHEAD;
#pragma unroll 2
            for (int kk = 0; kk < 128; ++kk) {
                const float tval = bf2f_raw(ts[hsw(s, kk)]);
                fma_row32(w2p + kk * EDIM, tval, facc);
            }
            __syncthreads();
        }
#pragma unroll
        for (int c = 0; c < DHEAD; ++c)
            xs[xsw(s, hh * DHEAD + c)] += facc[c] + b2[l * EDIM + hh * DHEAD + c];
        __syncthreads();
    }

    // ---- final LN on cls tokens -> out (fp32) ----
    if (tid < NCLS * 4) {
        const int ss = tid >> 2, gq = tid & 3;
        float vals[32];
        float sum = 0.f, sq = 0.f;
#pragma unroll
        for (int i = 0; i < 32; ++i) {
            const float v = xs[xsw(ss, gq * 32 + i)];
            vals[i] = v; sum += v; sq += v * v;
        }
        sum += __shfl_xor(sum, 1); sum += __shfl_xor(sum, 2);
        sq  += __shfl_xor(sq , 1); sq  += __shfl_xor(sq , 2);
        const float m = sum * (1.0f / 128.0f);
        const float r = rsqrtf(sq * (1.0f / 128.0f) - m * m + 1e-5f);
        float* op = out + (size_t)n * (NCLS * EDIM) + ss * EDIM;
#pragma unroll
        for (int i = 0; i < 32; ++i) {
            const int e = gq * 32 + i;
            op[e] = (vals[i] - m) * r * olng[e] + olnb[e];
        }
    }
}

extern "C" void kernel_launch(void* const* d_in, const int* in_sizes, int n_in,
                              void* d_out, int out_size, void* d_ws, size_t ws_size,
                              hipStream_t stream) {
    (void)n_in; (void)out_size; (void)d_ws; (void)ws_size;
    const float* emb  = (const float*)d_in[0];
    const float* cls  = (const float*)d_in[1];
    const float* ln1g = (const float*)d_in[2];
    const float* ln1b = (const float*)d_in[3];
    const float* wq   = (const float*)d_in[4];
    const float* bq   = (const float*)d_in[5];
    const float* wk   = (const float*)d_in[6];
    const float* bk   = (const float*)d_in[7];
    const float* wv   = (const float*)d_in[8];
    const float* bv   = (const float*)d_in[9];
    const float* wo   = (const float*)d_in[10];
    const float* bo   = (const float*)d_in[11];
    const float* ln2g = (const float*)d_in[12];
    const float* ln2b = (const float*)d_in[13];
    const float* w1   = (const float*)d_in[14];
    const float* b1   = (const float*)d_in[15];
    const float* w2   = (const float*)d_in[16];
    const float* b2   = (const float*)d_in[17];
    const float* olng = (const float*)d_in[18];
    const float* olnb = (const float*)d_in[19];
    const int*   dvec = (const int*)d_in[20];
    float* out = (float*)d_out;

    const int N = in_sizes[0] / (SEQ * EDIM);   // B*T = 4096
    hipLaunchKernelGGL(row_former, dim3(N), dim3(256), 0, stream,
                       emb, cls, ln1g, ln1b, wq, bq, wk, bk, wv, bv, wo, bo,
                       ln2g, ln2b, w1, b1, w2, b2, olng, olnb, dvec, out);
}

// Round 5
// 2954.151 us; speedup vs baseline: 5.2809x; 5.2809x over previous
//
#include <hip/hip_runtime.h>
#include <hip/hip_bf16.h>

#define NLAYER 3
#define EDIM   128
#define FFDIM  256
#define NCLS   4
#define SEQ    64

typedef unsigned short u16;
typedef unsigned int   u32;
typedef short bf16x8 __attribute__((ext_vector_type(8)));
typedef float f32x4  __attribute__((ext_vector_type(4)));

union U4F { uint4 u; bf16x8 s; };

__device__ __forceinline__ u16 f2bf(float f) {
    __hip_bfloat16 h = __float2bfloat16(f);
    union { __hip_bfloat16 h; u16 u; } c; c.h = h; return c.u;
}
__device__ __forceinline__ float bf2f(u16 u) {
    union { u32 i; float f; } c; c.i = ((u32)u) << 16; return c.f;
}

// ---------------- prep: fp32 weights -> bf16 [out][in] in d_ws -------------------
// ws (bf16 elems): [0)      qkvT [L][384][128]  (q 0-127, k 128-255, v 256-383)
//                  [147456) woT  [L][128][128]
//                  [196608) w1T  [L][256][128]
//                  [294912) w2T  [L][2ff][128][128]   (k-half-major)
__global__ void prep_weights(const float* __restrict__ wq, const float* __restrict__ wk,
                             const float* __restrict__ wv, const float* __restrict__ wo,
                             const float* __restrict__ w1, const float* __restrict__ w2,
                             u16* __restrict__ ws) {
    const int idx = blockIdx.x * 256 + threadIdx.x;
    float v;
    if (idx < 147456) {
        const int li = idx / 49152, r = idx % 49152, n = r >> 7, kk = r & 127;
        const int mat = n >> 7, nn = n & 127;
        const float* src = (mat == 0) ? wq : ((mat == 1) ? wk : wv);
        v = src[li * 16384 + kk * 128 + nn];
    } else if (idx < 196608) {
        const int j = idx - 147456, li = j / 16384, r = j % 16384, n = r >> 7, kk = r & 127;
        v = wo[li * 16384 + kk * 128 + n];
    } else if (idx < 294912) {
        const int j = idx - 196608, li = j / 32768, r = j % 32768, n = r >> 7, kk = r & 127;
        v = w1[li * 32768 + kk * 256 + n];
    } else {
        const int j = idx - 294912, li = j / 32768, r = j % 32768;
        const int ff = r >> 14, q = r & 16383, n = q >> 7, kk = q & 127;
        v = w2[li * 32768 + (ff * 128 + kk) * 128 + n];
    }
    ws[idx] = f2bf(v);
}

// ---------------- LDS: 4096 uint4 chunks = 64 KB, phase-multiplexed --------------
//  LN-out A: hi [0,1024), lo [1024,2048)   [64m][16c8]  m*16 + (c8 ^ (m&7))
//  q [0,1024), k [1024,2048)  per head [64m][4c8]  base + h*256 + m*4 + (c8 ^ (m&3))
//  v^T [2048,3072)            per head [32c][8c8]  2048 + h*256 + c*8 + (c8 ^ (c&7))
//  P [0,2048)                 per head [64m][8c8]  w*512 + m*8 + (c8 ^ (m&7))
//  O [3072,4096)              [64m][16c8]          3072 + m*16 + (c8 ^ (m&7))
//  gelu-t [2048,3072)         [64m][16c8]          2048 + m*16 + (c8 ^ (m&7))
//  fp32 relay [0,2048)        [64m][128f]          lds32: m*128 + ((c4 ^ (m&31))<<2) + (col&3)

// C[64x128] += A[64x128(x2 if SPLIT)] @ Bt[128x128]; A from LDS (aHi, lo at +1024),
// B-fragments loaded DIRECTLY from global (bsrc rows of 16 uint4, L2-hot).
template <bool SPLIT>
__device__ __forceinline__ void mmB(const uint4* lds, int aHi, const uint4* __restrict__ bsrc,
                                    int l16, int quad, int mp, int np, f32x4 acc[2][4]) {
#pragma unroll
    for (int ks = 0; ks < 4; ++ks) {
        bf16x8 ah[2], al[2];
#pragma unroll
        for (int t = 0; t < 2; ++t) {
            const int m = (mp * 2 + t) * 16 + l16;
            U4F x; x.u = lds[aHi + m * 16 + ((ks * 4 + quad) ^ (m & 7))];
            ah[t] = x.s;
            if (SPLIT) {
                U4F y; y.u = lds[aHi + 1024 + m * 16 + ((ks * 4 + quad) ^ (m & 7))];
                al[t] = y.s;
            }
        }
#pragma unroll
        for (int ntl = 0; ntl < 4; ++ntl) {
            const int nr = np * 64 + ntl * 16 + l16;
            U4F b; b.u = bsrc[(size_t)nr * 16 + (ks * 4 + quad)];
#pragma unroll
            for (int t = 0; t < 2; ++t) {
                acc[t][ntl] = __builtin_amdgcn_mfma_f32_16x16x32_bf16(ah[t], b.s, acc[t][ntl], 0, 0, 0);
                if (SPLIT)
                    acc[t][ntl] = __builtin_amdgcn_mfma_f32_16x16x32_bf16(al[t], b.s, acc[t][ntl], 0, 0, 0);
            }
        }
    }
}

__global__ void __launch_bounds__(256, 2)
row_former(const float* __restrict__ emb,  const float* __restrict__ cls,
           const float* __restrict__ ln1g, const float* __restrict__ ln1b,
           const float* __restrict__ bq,   const float* __restrict__ bk,
           const float* __restrict__ bv,   const float* __restrict__ bo,
           const float* __restrict__ ln2g, const float* __restrict__ ln2b,
           const float* __restrict__ b1,   const float* __restrict__ b2,
           const float* __restrict__ olng, const float* __restrict__ olnb,
           const int* __restrict__ dvec,   const u16* __restrict__ ws,
           float* __restrict__ out) {
    __shared__ uint4 lds[4096];
    u16*   lds16 = (u16*)lds;
    float* lds32 = (float*)lds;

    const int n    = blockIdx.x;
    const int tid  = threadIdx.x;
    const int w    = tid >> 6;
    const int lane = tid & 63;
    const int l16  = lane & 15;
    const int quad = lane >> 4;
    const int mp   = w & 1;
    const int np   = w >> 1;
    const int tok  = w * 16 + l16;
    const int lim  = dvec[n >> 10] + NCLS;

    const uint4* wsQ  = (const uint4*)ws;
    const uint4* wsO  = (const uint4*)(ws + 147456);
    const uint4* wsF1 = (const uint4*)(ws + 196608);
    const uint4* wsF2 = (const uint4*)(ws + 294912);

    // residual stream in registers: xs[i] = x[tok][quad*32 + i]
    float xs[32];
    {
        const float* srcrow = (tok < NCLS) ? (cls + tok * EDIM)
                                           : (emb + (size_t)n * (SEQ * EDIM) + tok * EDIM);
#pragma unroll
        for (int i = 0; i < 8; ++i) {
            const float4 v = *(const float4*)(srcrow + quad * 32 + i * 4);
            xs[i * 4 + 0] = v.x; xs[i * 4 + 1] = v.y; xs[i * 4 + 2] = v.z; xs[i * 4 + 3] = v.w;
        }
    }

#pragma unroll 1
    for (int l = 0; l < NLAYER; ++l) {
        // ---------- LN1 -> split bf16 A: hi [0,1024), lo [1024,2048) ----------
        {
            float sum = 0.f, sq = 0.f;
#pragma unroll
            for (int i = 0; i < 32; ++i) { sum += xs[i]; sq += xs[i] * xs[i]; }
            sum += __shfl_xor(sum, 16); sum += __shfl_xor(sum, 32);
            sq  += __shfl_xor(sq , 16); sq  += __shfl_xor(sq , 32);
            const float mean = sum * (1.f / 128.f);
            const float r = rsqrtf(sq * (1.f / 128.f) - mean * mean + 1e-5f);
            const float* g = ln1g + l * EDIM;
            const float* b = ln1b + l * EDIM;
#pragma unroll
            for (int i4 = 0; i4 < 4; ++i4) {
                u32 ph[4], pl[4];
#pragma unroll
                for (int p = 0; p < 4; ++p) {
                    u32 hl = 0, ll = 0;
#pragma unroll
                    for (int e = 0; e < 2; ++e) {
                        const int c = quad * 32 + i4 * 8 + p * 2 + e;
                        const float o = (xs[i4 * 8 + p * 2 + e] - mean) * r * g[c] + b[c];
                        const u32 hb = f2bf(o);
                        const u32 lb = f2bf(o - bf2f((u16)hb));
                        hl |= hb << (16 * e); ll |= lb << (16 * e);
                    }
                    ph[p] = hl; pl[p] = ll;
                }
                const int cc = (quad * 4 + i4) ^ (tok & 7);
                uint4 uh; uh.x = ph[0]; uh.y = ph[1]; uh.z = ph[2]; uh.w = ph[3];
                uint4 ul; ul.x = pl[0]; ul.y = pl[1]; ul.z = pl[2]; ul.w = pl[3];
                lds[tok * 16 + cc]        = uh;
                lds[1024 + tok * 16 + cc] = ul;
            }
        }
        __syncthreads();   // A visible

        // ---------- QKV: 3 split-A matmuls, B direct from global ----------
        f32x4 qa[2][4], ka[2][4], va[2][4];
        {
            const f32x4 z = {0.f, 0.f, 0.f, 0.f};
#pragma unroll
            for (int a = 0; a < 2; ++a)
#pragma unroll
                for (int b = 0; b < 4; ++b) { qa[a][b] = z; ka[a][b] = z; va[a][b] = z; }
        }
        mmB<true>(lds, 0, wsQ + (size_t)(l * 384 + 0) * 16,   l16, quad, mp, np, qa);
        mmB<true>(lds, 0, wsQ + (size_t)(l * 384 + 128) * 16, l16, quad, mp, np, ka);
        mmB<true>(lds, 0, wsQ + (size_t)(l * 384 + 256) * 16, l16, quad, mp, np, va);

        // bias + RoPE in C-layout regs
        {
#pragma unroll
            for (int ntl = 0; ntl < 4; ++ntl) {
                const int nn = np * 64 + ntl * 16 + l16;
                const float bqv = bq[l * EDIM + nn], bkv = bk[l * EDIM + nn], bvv = bv[l * EDIM + nn];
#pragma unroll
                for (int a = 0; a < 2; ++a)
#pragma unroll
                    for (int r = 0; r < 4; ++r) {
                        qa[a][ntl][r] += bqv; ka[a][ntl][r] += bkv; va[a][ntl][r] += bvv;
                    }
            }
            const float invf = __expf((float)l16 * -0.71955784156064f);  // 1e5^(-l16/16)
#pragma unroll
            for (int a = 0; a < 2; ++a)
#pragma unroll
                for (int r = 0; r < 4; ++r) {
                    const int m = (mp * 2 + a) * 16 + quad * 4 + r;
                    float sn, cs;
                    sincosf((float)m * invf, &sn, &cs);
#pragma unroll
                    for (int pg = 0; pg < 4; pg += 2) {
                        const float q1 = qa[a][pg][r], q2 = qa[a][pg + 1][r];
                        qa[a][pg][r]     = q1 * cs - q2 * sn;
                        qa[a][pg + 1][r] = q2 * cs + q1 * sn;
                        const float k1 = ka[a][pg][r], k2 = ka[a][pg + 1][r];
                        ka[a][pg][r]     = k1 * cs - k2 * sn;
                        ka[a][pg + 1][r] = k2 * cs + k1 * sn;
                    }
                }
        }
        __syncthreads();   // all A reads of QKV done before q/k overwrite [0,2048)

        // scatter q->[0,1024), k->[1024,2048), v^T->[2048,3072)
#pragma unroll
        for (int a = 0; a < 2; ++a)
#pragma unroll
            for (int ntl = 0; ntl < 4; ++ntl) {
                const int h   = np * 2 + (ntl >> 1);
                const int cin = (ntl & 1) * 16 + l16;
                const int c8q = cin >> 3;
#pragma unroll
                for (int r = 0; r < 4; ++r) {
                    const int m = (mp * 2 + a) * 16 + quad * 4 + r;
                    lds16[(h * 256 + m * 4 + (c8q ^ (m & 3))) * 8 + (cin & 7)]        = f2bf(qa[a][ntl][r]);
                    lds16[(1024 + h * 256 + m * 4 + (c8q ^ (m & 3))) * 8 + (cin & 7)] = f2bf(ka[a][ntl][r]);
                    lds16[(2048 + h * 256 + cin * 8 + ((m >> 3) ^ (cin & 7))) * 8 + (m & 7)] = f2bf(va[a][ntl][r]);
                }
            }
        __syncthreads();

        // ---------- attention: wave w = head w ----------
        float rl[4][4];
        {
            bf16x8 qf[4], kf[4];
#pragma unroll
            for (int mt = 0; mt < 4; ++mt) {
                const int m = mt * 16 + l16;
                U4F t; t.u = lds[w * 256 + m * 4 + (quad ^ (m & 3))];
                qf[mt] = t.s;
            }
#pragma unroll
            for (int nt = 0; nt < 4; ++nt) {
                const int nr = nt * 16 + l16;
                U4F t; t.u = lds[1024 + w * 256 + nr * 4 + (quad ^ (nr & 3))];
                kf[nt] = t.s;
            }
            f32x4 sf[4][4];
            const f32x4 z = {0.f, 0.f, 0.f, 0.f};
#pragma unroll
            for (int mt = 0; mt < 4; ++mt)
#pragma unroll
                for (int nt = 0; nt < 4; ++nt)
                    sf[mt][nt] = __builtin_amdgcn_mfma_f32_16x16x32_bf16(qf[mt], kf[nt], z, 0, 0, 0);

            float msk[4];
#pragma unroll
            for (int nt = 0; nt < 4; ++nt) msk[nt] = (nt * 16 + l16 >= lim) ? -1e9f : 0.f;
#pragma unroll
            for (int mt = 0; mt < 4; ++mt)
#pragma unroll
                for (int nt = 0; nt < 4; ++nt)
#pragma unroll
                    for (int r = 0; r < 4; ++r)
                        sf[mt][nt][r] = sf[mt][nt][r] * 0.17677669529663687f + msk[nt];
#pragma unroll
            for (int mt = 0; mt < 4; ++mt)
#pragma unroll
                for (int r = 0; r < 4; ++r) {
                    float mx = fmaxf(fmaxf(sf[mt][0][r], sf[mt][1][r]), fmaxf(sf[mt][2][r], sf[mt][3][r]));
                    mx = fmaxf(mx, __shfl_xor(mx, 1)); mx = fmaxf(mx, __shfl_xor(mx, 2));
                    mx = fmaxf(mx, __shfl_xor(mx, 4)); mx = fmaxf(mx, __shfl_xor(mx, 8));
                    float s = 0.f;
#pragma unroll
                    for (int nt = 0; nt < 4; ++nt) {
                        sf[mt][nt][r] = __expf(sf[mt][nt][r] - mx);
                        s += sf[mt][nt][r];
                    }
                    s += __shfl_xor(s, 1); s += __shfl_xor(s, 2);
                    s += __shfl_xor(s, 4); s += __shfl_xor(s, 8);
                    rl[mt][r] = 1.0f / s;
                }
            __syncthreads();   // q/k reads (all waves) done before P overwrites [0,2048)
#pragma unroll
            for (int mt = 0; mt < 4; ++mt)
#pragma unroll
                for (int nt = 0; nt < 4; ++nt)
#pragma unroll
                    for (int r = 0; r < 4; ++r) {
                        const int m = mt * 16 + quad * 4 + r;
                        const int j = nt * 16 + l16;
                        lds16[(w * 512 + m * 8 + ((j >> 3) ^ (m & 7))) * 8 + (j & 7)] = f2bf(sf[mt][nt][r]);
                    }
        }
        __syncthreads();   // P visible before PV

        // PV -> O [3072,4096) (A-layout, normalized)
        {
            bf16x8 vf2[2][2];
#pragma unroll
            for (int ntl = 0; ntl < 2; ++ntl)
#pragma unroll
                for (int ks = 0; ks < 2; ++ks) {
                    const int c = ntl * 16 + l16;
                    U4F t; t.u = lds[2048 + w * 256 + c * 8 + ((ks * 4 + quad) ^ (c & 7))];
                    vf2[ntl][ks] = t.s;
                }
            f32x4 of[4][2];
            const f32x4 z = {0.f, 0.f, 0.f, 0.f};
#pragma unroll
            for (int mt = 0; mt < 4; ++mt) { of[mt][0] = z; of[mt][1] = z; }
#pragma unroll
            for (int mt = 0; mt < 4; ++mt)
#pragma unroll
                for (int ks = 0; ks < 2; ++ks) {
                    const int m = mt * 16 + l16;
                    U4F pa; pa.u = lds[w * 512 + m * 8 + ((ks * 4 + quad) ^ (m & 7))];
#pragma unroll
                    for (int ntl = 0; ntl < 2; ++ntl)
                        of[mt][ntl] = __builtin_amdgcn_mfma_f32_16x16x32_bf16(pa.s, vf2[ntl][ks], of[mt][ntl], 0, 0, 0);
                }
            // O writes go to [3072,4096): disjoint from P/v^T regions still being read
#pragma unroll
            for (int mt = 0; mt < 4; ++mt)
#pragma unroll
                for (int ntl = 0; ntl < 2; ++ntl)
#pragma unroll
                    for (int r = 0; r < 4; ++r) {
                        const int m   = mt * 16 + quad * 4 + r;
                        const int col = w * 32 + ntl * 16 + l16;
                        lds16[(3072 + m * 16 + ((col >> 3) ^ (m & 7))) * 8 + (col & 7)] = f2bf(of[mt][ntl][r] * rl[mt][r]);
                    }
        }
        __syncthreads();   // O visible; P/v^T dead

        // ---------- out projection (A=O, B=Wo global) + fp32 relay + residual ----
        {
            f32x4 oc[2][4];
            const f32x4 z = {0.f, 0.f, 0.f, 0.f};
#pragma unroll
            for (int a = 0; a < 2; ++a)
#pragma unroll
                for (int b = 0; b < 4; ++b) oc[a][b] = z;
            mmB<false>(lds, 3072, wsO + (size_t)(l * 128) * 16, l16, quad, mp, np, oc);
            // relay fp32 -> [0,2048) (P region: dead; disjoint from O reads)
#pragma unroll
            for (int ntl = 0; ntl < 4; ++ntl) {
                const int col = np * 64 + ntl * 16 + l16;
                const float bias = bo[l * EDIM + col];
                const int c4 = col >> 2;
#pragma unroll
                for (int a = 0; a < 2; ++a)
#pragma unroll
                    for (int r = 0; r < 4; ++r) {
                        const int m = (mp * 2 + a) * 16 + quad * 4 + r;
                        lds32[m * 128 + ((c4 ^ (m & 31)) << 2) + (col & 3)] = oc[a][ntl][r] + bias;
                    }
            }
            __syncthreads();   // relay visible
#pragma unroll
            for (int j = 0; j < 8; ++j) {
                const uint4 c = lds[tok * 32 + ((quad * 8 + j) ^ (tok & 31))];
                const float4 f = *(const float4*)&c;
                xs[j * 4 + 0] += f.x; xs[j * 4 + 1] += f.y; xs[j * 4 + 2] += f.z; xs[j * 4 + 3] += f.w;
            }
        }
        __syncthreads();   // relay reads done before LN2 overwrites [0,2048)

        // ---------- LN2 -> split bf16 A: hi [0,1024), lo [1024,2048) ----------
        {
            float sum = 0.f, sq = 0.f;
#pragma unroll
            for (int i = 0; i < 32; ++i) { sum += xs[i]; sq += xs[i] * xs[i]; }
            sum += __shfl_xor(sum, 16); sum += __shfl_xor(sum, 32);
            sq  += __shfl_xor(sq , 16); sq  += __shfl_xor(sq , 32);
            const float mean = sum * (1.f / 128.f);
            const float r = rsqrtf(sq * (1.f / 128.f) - mean * mean + 1e-5f);
            const float* g = ln2g + l * EDIM;
            const float* b = ln2b + l * EDIM;
#pragma unroll
            for (int i4 = 0; i4 < 4; ++i4) {
                u32 ph[4], pl[4];
#pragma unroll
                for (int p = 0; p < 4; ++p) {
                    u32 hl = 0, ll = 0;
#pragma unroll
                    for (int e = 0; e < 2; ++e) {
                        const int c = quad * 32 + i4 * 8 + p * 2 + e;
                        const float o = (xs[i4 * 8 + p * 2 + e] - mean) * r * g[c] + b[c];
                        const u32 hb = f2bf(o);
                        const u32 lb = f2bf(o - bf2f((u16)hb));
                        hl |= hb << (16 * e); ll |= lb << (16 * e);
                    }
                    ph[p] = hl; pl[p] = ll;
                }
                const int cc = (quad * 4 + i4) ^ (tok & 7);
                uint4 uh; uh.x = ph[0]; uh.y = ph[1]; uh.z = ph[2]; uh.w = ph[3];
                uint4 ul; ul.x = pl[0]; ul.y = pl[1]; ul.z = pl[2]; ul.w = pl[3];
                lds[tok * 16 + cc]        = uh;
                lds[1024 + tok * 16 + cc] = ul;
            }
        }
        __syncthreads();   // LN2 A visible

        // ---------- FFN: two 128-wide halves; B direct global, t [2048,3072) ------
        {
            f32x4 fa[2][4];
            const f32x4 z = {0.f, 0.f, 0.f, 0.f};
#pragma unroll
            for (int a = 0; a < 2; ++a)
#pragma unroll
                for (int b = 0; b < 4; ++b) fa[a][b] = z;
#pragma unroll 1
            for (int ff = 0; ff < 2; ++ff) {
                f32x4 tf[2][4];
#pragma unroll
                for (int a = 0; a < 2; ++a)
#pragma unroll
                    for (int b = 0; b < 4; ++b) tf[a][b] = z;
                mmB<true>(lds, 0, wsF1 + (size_t)(l * 256 + ff * 128) * 16, l16, quad, mp, np, tf);
                __syncthreads();   // prior-half t reads done before t overwrite
                // bias + gelu(tanh) -> t
#pragma unroll
                for (int a = 0; a < 2; ++a)
#pragma unroll
                    for (int ntl = 0; ntl < 4; ++ntl) {
                        const int nn = np * 64 + ntl * 16 + l16;
                        const float bb = b1[l * FFDIM + ff * 128 + nn];
#pragma unroll
                        for (int r = 0; r < 4; ++r) {
                            const float y = tf[a][ntl][r] + bb;
                            const float t = tanhf(0.7978845608028654f * (y + 0.044715f * y * y * y));
                            const float gl = 0.5f * y * (1.0f + t);
                            const int m = (mp * 2 + a) * 16 + quad * 4 + r;
                            lds16[(2048 + m * 16 + ((nn >> 3) ^ (m & 7))) * 8 + (nn & 7)] = f2bf(gl);
                        }
                    }
                __syncthreads();   // t visible
                mmB<false>(lds, 2048, wsF2 + (size_t)((l * 2 + ff) * 128) * 16, l16, quad, mp, np, fa);
            }
            __syncthreads();   // t reads + A reads done before relay overwrites [0,2048)
#pragma unroll
            for (int ntl = 0; ntl < 4; ++ntl) {
                const int col = np * 64 + ntl * 16 + l16;
                const float bias = b2[l * EDIM + col];
                const int c4 = col >> 2;
#pragma unroll
                for (int a = 0; a < 2; ++a)
#pragma unroll
                    for (int r = 0; r < 4; ++r) {
                        const int m = (mp * 2 + a) * 16 + quad * 4 + r;
                        lds32[m * 128 + ((c4 ^ (m & 31)) << 2) + (col & 3)] = fa[a][ntl][r] + bias;
                    }
            }
            __syncthreads();   // relay visible
#pragma unroll
            for (int j = 0; j < 8; ++j) {
                const uint4 c = lds[tok * 32 + ((quad * 8 + j) ^ (tok & 31))];
                const float4 f = *(const float4*)&c;
                xs[j * 4 + 0] += f.x; xs[j * 4 + 1] += f.y; xs[j * 4 + 2] += f.z; xs[j * 4 + 3] += f.w;
            }
            __syncthreads();   // relay reads done before next-layer LN1
        }
    }

    // ---------- final LN on cls tokens -> out (fp32) ----------
    if (w == 0) {
        float sum = 0.f, sq = 0.f;
#pragma unroll
        for (int i = 0; i < 32; ++i) { sum += xs[i]; sq += xs[i] * xs[i]; }
        sum += __shfl_xor(sum, 16); sum += __shfl_xor(sum, 32);
        sq  += __shfl_xor(sq , 16); sq  += __shfl_xor(sq , 32);
        const float mean = sum * (1.f / 128.f);
        const float r = rsqrtf(sq * (1.f / 128.f) - mean * mean + 1e-5f);
        if (l16 < NCLS) {
            float* op = out + (size_t)n * (NCLS * EDIM) + l16 * EDIM + quad * 32;
#pragma unroll
            for (int i = 0; i < 32; ++i) {
                const int c = quad * 32 + i;
                op[i] = (xs[i] - mean) * r * olng[c] + olnb[c];
            }
        }
    }
}

extern "C" void kernel_launch(void* const* d_in, const int* in_sizes, int n_in,
                              void* d_out, int out_size, void* d_ws, size_t ws_size,
                              hipStream_t stream) {
    (void)n_in; (void)out_size; (void)ws_size;
    const float* emb  = (const float*)d_in[0];
    const float* cls  = (const float*)d_in[1];
    const float* ln1g = (const float*)d_in[2];
    const float* ln1b = (const float*)d_in[3];
    const float* wq   = (const float*)d_in[4];
    const float* bq   = (const float*)d_in[5];
    const float* wk   = (const float*)d_in[6];
    const float* bk   = (const float*)d_in[7];
    const float* wv   = (const float*)d_in[8];
    const float* bv   = (const float*)d_in[9];
    const float* wo   = (const float*)d_in[10];
    const float* bo   = (const float*)d_in[11];
    const float* ln2g = (const float*)d_in[12];
    const float* ln2b = (const float*)d_in[13];
    const float* w1   = (const float*)d_in[14];
    const float* b1   = (const float*)d_in[15];
    const float* w2   = (const float*)d_in[16];
    const float* b2   = (const float*)d_in[17];
    const float* olng = (const float*)d_in[18];
    const float* olnb = (const float*)d_in[19];
    const int*   dvec = (const int*)d_in[20];
    float* out = (float*)d_out;
    u16*   ws  = (u16*)d_ws;

    hipLaunchKernelGGL(prep_weights, dim3(1536), dim3(256), 0, stream,
                       wq, wk, wv, wo, w1, w2, ws);

    const int N = in_sizes[0] / (SEQ * EDIM);   // B*T = 4096
    hipLaunchKernelGGL(row_former, dim3(N), dim3(256), 0, stream,
                       emb, cls, ln1g, ln1b, bq, bk, bv, bo,
                       ln2g, ln2b, b1, b2, olng, olnb, dvec, ws, out);
}

// Round 6
// 2636.300 us; speedup vs baseline: 5.9176x; 1.1206x over previous
//
#include <hip/hip_runtime.h>
#include <hip/hip_bf16.h>

#define NLAYER 3
#define EDIM   128
#define FFDIM  256
#define NCLS   4
#define SEQ    64

typedef unsigned short u16;
typedef unsigned int   u32;
typedef short bf16x8 __attribute__((ext_vector_type(8)));
typedef float f32x4  __attribute__((ext_vector_type(4)));

union U4F { uint4 u; bf16x8 s; };

__device__ __forceinline__ u16 f2bf(float f) {
    __hip_bfloat16 h = __float2bfloat16(f);
    union { __hip_bfloat16 h; u16 u; } c; c.h = h; return c.u;
}
__device__ __forceinline__ float bf2f(u16 u) {
    union { u32 i; float f; } c; c.i = ((u32)u) << 16; return c.f;
}

// ---------------- prep: fp32 weights -> bf16, CHUNK-PLANE-MAJOR tiles ------------
// Each 128x128 B-block = 16384 bf16 elems, stored as [plane 0..15][row 0..127][e 0..7]
// where plane p covers input cols p*8..p*8+7 of row nr (one 16B MFMA fragment).
// A wave's fragment loads (16 lanes x consecutive nr) are 256B contiguous bursts.
// Block order in ws (bf16 elems):
//   [0)      qkv: (l*3+mat)*16384, mat=0,1,2 (q,k,v)
//   [147456) wo:  l*16384
//   [196608) w1:  (l*2+ff)*16384
//   [294912) w2:  (l*2+ff)*16384   (ff = k-half)
__global__ void prep_weights(const float* __restrict__ wq, const float* __restrict__ wk,
                             const float* __restrict__ wv, const float* __restrict__ wo,
                             const float* __restrict__ w1, const float* __restrict__ w2,
                             u16* __restrict__ ws) {
    const int idx = blockIdx.x * 256 + threadIdx.x;
    float v;
    if (idx < 147456) {
        const int li = idx / 49152, r = idx % 49152, mat = r >> 14, j = r & 16383;
        const int plane = j >> 10, nr = (j >> 3) & 127, e = j & 7;
        const float* src = (mat == 0) ? wq : ((mat == 1) ? wk : wv);
        v = src[li * 16384 + (plane * 8 + e) * 128 + nr];
    } else if (idx < 196608) {
        const int j0 = idx - 147456, li = j0 / 16384, j = j0 % 16384;
        const int plane = j >> 10, nr = (j >> 3) & 127, e = j & 7;
        v = wo[li * 16384 + (plane * 8 + e) * 128 + nr];
    } else if (idx < 294912) {
        const int j0 = idx - 196608, li = j0 / 32768, r = j0 % 32768, ff = r >> 14, j = r & 16383;
        const int plane = j >> 10, nr = (j >> 3) & 127, e = j & 7;
        v = w1[li * 32768 + (plane * 8 + e) * 256 + ff * 128 + nr];
    } else {
        const int j0 = idx - 294912, li = j0 / 32768, r = j0 % 32768, ff = r >> 14, j = r & 16383;
        const int plane = j >> 10, nr = (j >> 3) & 127, e = j & 7;
        v = w2[li * 32768 + (ff * 128 + plane * 8 + e) * 128 + nr];
    }
    ws[idx] = f2bf(v);
}

// ---------------- LDS: 4096 uint4 chunks = 64 KB, phase-multiplexed --------------
//  LN-out A: hi [0,1024), lo [1024,2048)   [64m][16c8]  m*16 + (c8 ^ (m&7))
//  q [0,1024), k [1024,2048)  per head [64m][4c8]  base + h*256 + m*4 + (c8 ^ (m&3))
//  v^T [2048,3072)            per head [32c][8c8]  2048 + h*256 + c*8 + (c8 ^ (c&7))
//  P [0,2048)                 per head [64m][8c8]  w*512 + m*8 + (c8 ^ (m&7))
//  O [3072,4096)              [64m][16c8]          3072 + m*16 + (c8 ^ (m&7))
//  gelu-t [2048,3072)         [64m][16c8]          2048 + m*16 + (c8 ^ (m&7))
//  fp32 relay [0,2048)        [64m][128f]          lds32: m*128 + ((c4 ^ (m&31))<<2) + (col&3)

// C[64x128] += A[64x128(x2 if SPLIT)] @ Bt[128x128]; A from LDS (aHi, lo at +1024),
// B-fragments direct from global, chunk-plane-major: bsrc[plane*128 + nr].
template <bool SPLIT>
__device__ __forceinline__ void mmB(const uint4* lds, int aHi, const uint4* __restrict__ bsrc,
                                    int l16, int quad, int mp, int np, f32x4 acc[2][4]) {
#pragma unroll
    for (int ks = 0; ks < 4; ++ks) {
        bf16x8 ah[2], al[2];
#pragma unroll
        for (int t = 0; t < 2; ++t) {
            const int m = (mp * 2 + t) * 16 + l16;
            U4F x; x.u = lds[aHi + m * 16 + ((ks * 4 + quad) ^ (m & 7))];
            ah[t] = x.s;
            if (SPLIT) {
                U4F y; y.u = lds[aHi + 1024 + m * 16 + ((ks * 4 + quad) ^ (m & 7))];
                al[t] = y.s;
            }
        }
#pragma unroll
        for (int ntl = 0; ntl < 4; ++ntl) {
            const int nr = np * 64 + ntl * 16 + l16;
            U4F b; b.u = bsrc[((ks * 4 + quad) << 7) + nr];
#pragma unroll
            for (int t = 0; t < 2; ++t) {
                acc[t][ntl] = __builtin_amdgcn_mfma_f32_16x16x32_bf16(ah[t], b.s, acc[t][ntl], 0, 0, 0);
                if (SPLIT)
                    acc[t][ntl] = __builtin_amdgcn_mfma_f32_16x16x32_bf16(al[t], b.s, acc[t][ntl], 0, 0, 0);
            }
        }
    }
}

__global__ void __launch_bounds__(256, 2)
row_former(const float* __restrict__ emb,  const float* __restrict__ cls,
           const float* __restrict__ ln1g, const float* __restrict__ ln1b,
           const float* __restrict__ bq,   const float* __restrict__ bk,
           const float* __restrict__ bv,   const float* __restrict__ bo,
           const float* __restrict__ ln2g, const float* __restrict__ ln2b,
           const float* __restrict__ b1,   const float* __restrict__ b2,
           const float* __restrict__ olng, const float* __restrict__ olnb,
           const int* __restrict__ dvec,   const u16* __restrict__ ws,
           float* __restrict__ out) {
    __shared__ uint4 lds[4096];
    u16*   lds16 = (u16*)lds;
    float* lds32 = (float*)lds;

    const int n    = blockIdx.x;
    const int tid  = threadIdx.x;
    const int w    = tid >> 6;
    const int lane = tid & 63;
    const int l16  = lane & 15;
    const int quad = lane >> 4;
    const int mp   = w & 1;
    const int np   = w >> 1;
    const int tok  = w * 16 + l16;
    const int lim  = dvec[n >> 10] + NCLS;

    const uint4* wsQ  = (const uint4*)ws;                    // (l*3+mat)*2048
    const uint4* wsO  = (const uint4*)(ws + 147456);         // l*2048
    const uint4* wsF1 = (const uint4*)(ws + 196608);         // (l*2+ff)*2048
    const uint4* wsF2 = (const uint4*)(ws + 294912);         // (l*2+ff)*2048

    // residual stream in registers: xs[i] = x[tok][quad*32 + i]
    float xs[32];
    {
        const float* srcrow = (tok < NCLS) ? (cls + tok * EDIM)
                                           : (emb + (size_t)n * (SEQ * EDIM) + tok * EDIM);
#pragma unroll
        for (int i = 0; i < 8; ++i) {
            const float4 v = *(const float4*)(srcrow + quad * 32 + i * 4);
            xs[i * 4 + 0] = v.x; xs[i * 4 + 1] = v.y; xs[i * 4 + 2] = v.z; xs[i * 4 + 3] = v.w;
        }
    }

#pragma unroll 1
    for (int l = 0; l < NLAYER; ++l) {
        // ---------- LN1 -> split bf16 A: hi [0,1024), lo [1024,2048) ----------
        {
            float sum = 0.f, sq = 0.f;
#pragma unroll
            for (int i = 0; i < 32; ++i) { sum += xs[i]; sq += xs[i] * xs[i]; }
            sum += __shfl_xor(sum, 16); sum += __shfl_xor(sum, 32);
            sq  += __shfl_xor(sq , 16); sq  += __shfl_xor(sq , 32);
            const float mean = sum * (1.f / 128.f);
            const float r = rsqrtf(sq * (1.f / 128.f) - mean * mean + 1e-5f);
            const float* g = ln1g + l * EDIM;
            const float* b = ln1b + l * EDIM;
#pragma unroll
            for (int i4 = 0; i4 < 4; ++i4) {
                u32 ph[4], pl[4];
#pragma unroll
                for (int p = 0; p < 4; ++p) {
                    u32 hl = 0, ll = 0;
#pragma unroll
                    for (int e = 0; e < 2; ++e) {
                        const int c = quad * 32 + i4 * 8 + p * 2 + e;
                        const float o = (xs[i4 * 8 + p * 2 + e] - mean) * r * g[c] + b[c];
                        const u32 hb = f2bf(o);
                        const u32 lb = f2bf(o - bf2f((u16)hb));
                        hl |= hb << (16 * e); ll |= lb << (16 * e);
                    }
                    ph[p] = hl; pl[p] = ll;
                }
                const int cc = (quad * 4 + i4) ^ (tok & 7);
                uint4 uh; uh.x = ph[0]; uh.y = ph[1]; uh.z = ph[2]; uh.w = ph[3];
                uint4 ul; ul.x = pl[0]; ul.y = pl[1]; ul.z = pl[2]; ul.w = pl[3];
                lds[tok * 16 + cc]        = uh;
                lds[1024 + tok * 16 + cc] = ul;
            }
        }
        __syncthreads();   // A visible

        // ---------- QKV: 3 split-A matmuls, B direct from global (coalesced) -----
        f32x4 qa[2][4], ka[2][4], va[2][4];
        {
            const f32x4 z = {0.f, 0.f, 0.f, 0.f};
#pragma unroll
            for (int a = 0; a < 2; ++a)
#pragma unroll
                for (int b = 0; b < 4; ++b) { qa[a][b] = z; ka[a][b] = z; va[a][b] = z; }
        }
        mmB<true>(lds, 0, wsQ + (size_t)(l * 3 + 0) * 2048, l16, quad, mp, np, qa);
        mmB<true>(lds, 0, wsQ + (size_t)(l * 3 + 1) * 2048, l16, quad, mp, np, ka);
        mmB<true>(lds, 0, wsQ + (size_t)(l * 3 + 2) * 2048, l16, quad, mp, np, va);

        // bias + RoPE in C-layout regs
        {
#pragma unroll
            for (int ntl = 0; ntl < 4; ++ntl) {
                const int nn = np * 64 + ntl * 16 + l16;
                const float bqv = bq[l * EDIM + nn], bkv = bk[l * EDIM + nn], bvv = bv[l * EDIM + nn];
#pragma unroll
                for (int a = 0; a < 2; ++a)
#pragma unroll
                    for (int r = 0; r < 4; ++r) {
                        qa[a][ntl][r] += bqv; ka[a][ntl][r] += bkv; va[a][ntl][r] += bvv;
                    }
            }
            const float invf = __expf((float)l16 * -0.71955784156064f);  // 1e5^(-l16/16)
#pragma unroll
            for (int a = 0; a < 2; ++a)
#pragma unroll
                for (int r = 0; r < 4; ++r) {
                    const int m = (mp * 2 + a) * 16 + quad * 4 + r;
                    float sn, cs;
                    sincosf((float)m * invf, &sn, &cs);
#pragma unroll
                    for (int pg = 0; pg < 4; pg += 2) {
                        const float q1 = qa[a][pg][r], q2 = qa[a][pg + 1][r];
                        qa[a][pg][r]     = q1 * cs - q2 * sn;
                        qa[a][pg + 1][r] = q2 * cs + q1 * sn;
                        const float k1 = ka[a][pg][r], k2 = ka[a][pg + 1][r];
                        ka[a][pg][r]     = k1 * cs - k2 * sn;
                        ka[a][pg + 1][r] = k2 * cs + k1 * sn;
                    }
                }
        }
        __syncthreads();   // all A reads of QKV done before q/k overwrite [0,2048)

        // scatter q->[0,1024), k->[1024,2048), v^T->[2048,3072)
#pragma unroll
        for (int a = 0; a < 2; ++a)
#pragma unroll
            for (int ntl = 0; ntl < 4; ++ntl) {
                const int h   = np * 2 + (ntl >> 1);
                const int cin = (ntl & 1) * 16 + l16;
                const int c8q = cin >> 3;
#pragma unroll
                for (int r = 0; r < 4; ++r) {
                    const int m = (mp * 2 + a) * 16 + quad * 4 + r;
                    lds16[(h * 256 + m * 4 + (c8q ^ (m & 3))) * 8 + (cin & 7)]        = f2bf(qa[a][ntl][r]);
                    lds16[(1024 + h * 256 + m * 4 + (c8q ^ (m & 3))) * 8 + (cin & 7)] = f2bf(ka[a][ntl][r]);
                    lds16[(2048 + h * 256 + cin * 8 + ((m >> 3) ^ (cin & 7))) * 8 + (m & 7)] = f2bf(va[a][ntl][r]);
                }
            }
        __syncthreads();

        // ---------- attention: wave w = head w ----------
        float rl[4][4];
        {
            bf16x8 qf[4], kf[4];
#pragma unroll
            for (int mt = 0; mt < 4; ++mt) {
                const int m = mt * 16 + l16;
                U4F t; t.u = lds[w * 256 + m * 4 + (quad ^ (m & 3))];
                qf[mt] = t.s;
            }
#pragma unroll
            for (int nt = 0; nt < 4; ++nt) {
                const int nr = nt * 16 + l16;
                U4F t; t.u = lds[1024 + w * 256 + nr * 4 + (quad ^ (nr & 3))];
                kf[nt] = t.s;
            }
            f32x4 sf[4][4];
            const f32x4 z = {0.f, 0.f, 0.f, 0.f};
#pragma unroll
            for (int mt = 0; mt < 4; ++mt)
#pragma unroll
                for (int nt = 0; nt < 4; ++nt)
                    sf[mt][nt] = __builtin_amdgcn_mfma_f32_16x16x32_bf16(qf[mt], kf[nt], z, 0, 0, 0);

            float msk[4];
#pragma unroll
            for (int nt = 0; nt < 4; ++nt) msk[nt] = (nt * 16 + l16 >= lim) ? -1e9f : 0.f;
#pragma unroll
            for (int mt = 0; mt < 4; ++mt)
#pragma unroll
                for (int nt = 0; nt < 4; ++nt)
#pragma unroll
                    for (int r = 0; r < 4; ++r)
                        sf[mt][nt][r] = sf[mt][nt][r] * 0.17677669529663687f + msk[nt];
#pragma unroll
            for (int mt = 0; mt < 4; ++mt)
#pragma unroll
                for (int r = 0; r < 4; ++r) {
                    float mx = fmaxf(fmaxf(sf[mt][0][r], sf[mt][1][r]), fmaxf(sf[mt][2][r], sf[mt][3][r]));
                    mx = fmaxf(mx, __shfl_xor(mx, 1)); mx = fmaxf(mx, __shfl_xor(mx, 2));
                    mx = fmaxf(mx, __shfl_xor(mx, 4)); mx = fmaxf(mx, __shfl_xor(mx, 8));
                    float s = 0.f;
#pragma unroll
                    for (int nt = 0; nt < 4; ++nt) {
                        sf[mt][nt][r] = __expf(sf[mt][nt][r] - mx);
                        s += sf[mt][nt][r];
                    }
                    s += __shfl_xor(s, 1); s += __shfl_xor(s, 2);
                    s += __shfl_xor(s, 4); s += __shfl_xor(s, 8);
                    rl[mt][r] = 1.0f / s;
                }
            __syncthreads();   // q/k reads (all waves) done before P overwrites [0,2048)
#pragma unroll
            for (int mt = 0; mt < 4; ++mt)
#pragma unroll
                for (int nt = 0; nt < 4; ++nt)
#pragma unroll
                    for (int r = 0; r < 4; ++r) {
                        const int m = mt * 16 + quad * 4 + r;
                        const int j = nt * 16 + l16;
                        lds16[(w * 512 + m * 8 + ((j >> 3) ^ (m & 7))) * 8 + (j & 7)] = f2bf(sf[mt][nt][r]);
                    }
        }
        __syncthreads();   // P visible before PV

        // PV -> O [3072,4096) (A-layout, normalized)
        {
            bf16x8 vf2[2][2];
#pragma unroll
            for (int ntl = 0; ntl < 2; ++ntl)
#pragma unroll
                for (int ks = 0; ks < 2; ++ks) {
                    const int c = ntl * 16 + l16;
                    U4F t; t.u = lds[2048 + w * 256 + c * 8 + ((ks * 4 + quad) ^ (c & 7))];
                    vf2[ntl][ks] = t.s;
                }
            f32x4 of[4][2];
            const f32x4 z = {0.f, 0.f, 0.f, 0.f};
#pragma unroll
            for (int mt = 0; mt < 4; ++mt) { of[mt][0] = z; of[mt][1] = z; }
#pragma unroll
            for (int mt = 0; mt < 4; ++mt)
#pragma unroll
                for (int ks = 0; ks < 2; ++ks) {
                    const int m = mt * 16 + l16;
                    U4F pa; pa.u = lds[w * 512 + m * 8 + ((ks * 4 + quad) ^ (m & 7))];
#pragma unroll
                    for (int ntl = 0; ntl < 2; ++ntl)
                        of[mt][ntl] = __builtin_amdgcn_mfma_f32_16x16x32_bf16(pa.s, vf2[ntl][ks], of[mt][ntl], 0, 0, 0);
                }
            // O writes go to [3072,4096): disjoint from P/v^T regions still being read
#pragma unroll
            for (int mt = 0; mt < 4; ++mt)
#pragma unroll
                for (int ntl = 0; ntl < 2; ++ntl)
#pragma unroll
                    for (int r = 0; r < 4; ++r) {
                        const int m   = mt * 16 + quad * 4 + r;
                        const int col = w * 32 + ntl * 16 + l16;
                        lds16[(3072 + m * 16 + ((col >> 3) ^ (m & 7))) * 8 + (col & 7)] = f2bf(of[mt][ntl][r] * rl[mt][r]);
                    }
        }
        __syncthreads();   // O visible; P/v^T dead

        // ---------- out projection (A=O, B=Wo global) + fp32 relay + residual ----
        {
            f32x4 oc[2][4];
            const f32x4 z = {0.f, 0.f, 0.f, 0.f};
#pragma unroll
            for (int a = 0; a < 2; ++a)
#pragma unroll
                for (int b = 0; b < 4; ++b) oc[a][b] = z;
            mmB<false>(lds, 3072, wsO + (size_t)l * 2048, l16, quad, mp, np, oc);
            // relay fp32 -> [0,2048) (P region: dead; disjoint from O reads)
#pragma unroll
            for (int ntl = 0; ntl < 4; ++ntl) {
                const int col = np * 64 + ntl * 16 + l16;
                const float bias = bo[l * EDIM + col];
                const int c4 = col >> 2;
#pragma unroll
                for (int a = 0; a < 2; ++a)
#pragma unroll
                    for (int r = 0; r < 4; ++r) {
                        const int m = (mp * 2 + a) * 16 + quad * 4 + r;
                        lds32[m * 128 + ((c4 ^ (m & 31)) << 2) + (col & 3)] = oc[a][ntl][r] + bias;
                    }
            }
            __syncthreads();   // relay visible
#pragma unroll
            for (int j = 0; j < 8; ++j) {
                const uint4 c = lds[tok * 32 + ((quad * 8 + j) ^ (tok & 31))];
                const float4 f = *(const float4*)&c;
                xs[j * 4 + 0] += f.x; xs[j * 4 + 1] += f.y; xs[j * 4 + 2] += f.z; xs[j * 4 + 3] += f.w;
            }
        }
        __syncthreads();   // relay reads done before LN2 overwrites [0,2048)

        // ---------- LN2 -> split bf16 A: hi [0,1024), lo [1024,2048) ----------
        {
            float sum = 0.f, sq = 0.f;
#pragma unroll
            for (int i = 0; i < 32; ++i) { sum += xs[i]; sq += xs[i] * xs[i]; }
            sum += __shfl_xor(sum, 16); sum += __shfl_xor(sum, 32);
            sq  += __shfl_xor(sq , 16); sq  += __shfl_xor(sq , 32);
            const float mean = sum * (1.f / 128.f);
            const float r = rsqrtf(sq * (1.f / 128.f) - mean * mean + 1e-5f);
            const float* g = ln2g + l * EDIM;
            const float* b = ln2b + l * EDIM;
#pragma unroll
            for (int i4 = 0; i4 < 4; ++i4) {
                u32 ph[4], pl[4];
#pragma unroll
                for (int p = 0; p < 4; ++p) {
                    u32 hl = 0, ll = 0;
#pragma unroll
                    for (int e = 0; e < 2; ++e) {
                        const int c = quad * 32 + i4 * 8 + p * 2 + e;
                        const float o = (xs[i4 * 8 + p * 2 + e] - mean) * r * g[c] + b[c];
                        const u32 hb = f2bf(o);
                        const u32 lb = f2bf(o - bf2f((u16)hb));
                        hl |= hb << (16 * e); ll |= lb << (16 * e);
                    }
                    ph[p] = hl; pl[p] = ll;
                }
                const int cc = (quad * 4 + i4) ^ (tok & 7);
                uint4 uh; uh.x = ph[0]; uh.y = ph[1]; uh.z = ph[2]; uh.w = ph[3];
                uint4 ul; ul.x = pl[0]; ul.y = pl[1]; ul.z = pl[2]; ul.w = pl[3];
                lds[tok * 16 + cc]        = uh;
                lds[1024 + tok * 16 + cc] = ul;
            }
        }
        __syncthreads();   // LN2 A visible

        // ---------- FFN: two 128-wide halves; B direct global, t [2048,3072) ------
        {
            f32x4 fa[2][4];
            const f32x4 z = {0.f, 0.f, 0.f, 0.f};
#pragma unroll
            for (int a = 0; a < 2; ++a)
#pragma unroll
                for (int b = 0; b < 4; ++b) fa[a][b] = z;
#pragma unroll 1
            for (int ff = 0; ff < 2; ++ff) {
                f32x4 tf[2][4];
#pragma unroll
                for (int a = 0; a < 2; ++a)
#pragma unroll
                    for (int b = 0; b < 4; ++b) tf[a][b] = z;
                mmB<true>(lds, 0, wsF1 + (size_t)(l * 2 + ff) * 2048, l16, quad, mp, np, tf);
                __syncthreads();   // prior-half t reads done before t overwrite
                // bias + gelu(tanh) -> t
#pragma unroll
                for (int a = 0; a < 2; ++a)
#pragma unroll
                    for (int ntl = 0; ntl < 4; ++ntl) {
                        const int nn = np * 64 + ntl * 16 + l16;
                        const float bb = b1[l * FFDIM + ff * 128 + nn];
#pragma unroll
                        for (int r = 0; r < 4; ++r) {
                            const float y = tf[a][ntl][r] + bb;
                            const float t = tanhf(0.7978845608028654f * (y + 0.044715f * y * y * y));
                            const float gl = 0.5f * y * (1.0f + t);
                            const int m = (mp * 2 + a) * 16 + quad * 4 + r;
                            lds16[(2048 + m * 16 + ((nn >> 3) ^ (m & 7))) * 8 + (nn & 7)] = f2bf(gl);
                        }
                    }
                __syncthreads();   // t visible
                mmB<false>(lds, 2048, wsF2 + (size_t)(l * 2 + ff) * 2048, l16, quad, mp, np, fa);
            }
            __syncthreads();   // t reads + A reads done before relay overwrites [0,2048)
#pragma unroll
            for (int ntl = 0; ntl < 4; ++ntl) {
                const int col = np * 64 + ntl * 16 + l16;
                const float bias = b2[l * EDIM + col];
                const int c4 = col >> 2;
#pragma unroll
                for (int a = 0; a < 2; ++a)
#pragma unroll
                    for (int r = 0; r < 4; ++r) {
                        const int m = (mp * 2 + a) * 16 + quad * 4 + r;
                        lds32[m * 128 + ((c4 ^ (m & 31)) << 2) + (col & 3)] = fa[a][ntl][r] + bias;
                    }
            }
            __syncthreads();   // relay visible
#pragma unroll
            for (int j = 0; j < 8; ++j) {
                const uint4 c = lds[tok * 32 + ((quad * 8 + j) ^ (tok & 31))];
                const float4 f = *(const float4*)&c;
                xs[j * 4 + 0] += f.x; xs[j * 4 + 1] += f.y; xs[j * 4 + 2] += f.z; xs[j * 4 + 3] += f.w;
            }
            __syncthreads();   // relay reads done before next-layer LN1
        }
    }

    // ---------- final LN on cls tokens -> out (fp32) ----------
    if (w == 0) {
        float sum = 0.f, sq = 0.f;
#pragma unroll
        for (int i = 0; i < 32; ++i) { sum += xs[i]; sq += xs[i] * xs[i]; }
        sum += __shfl_xor(sum, 16); sum += __shfl_xor(sum, 32);
        sq  += __shfl_xor(sq , 16); sq  += __shfl_xor(sq , 32);
        const float mean = sum * (1.f / 128.f);
        const float r = rsqrtf(sq * (1.f / 128.f) - mean * mean + 1e-5f);
        if (l16 < NCLS) {
            float* op = out + (size_t)n * (NCLS * EDIM) + l16 * EDIM + quad * 32;
#pragma unroll
            for (int i = 0; i < 32; ++i) {
                const int c = quad * 32 + i;
                op[i] = (xs[i] - mean) * r * olng[c] + olnb[c];
            }
        }
    }
}

extern "C" void kernel_launch(void* const* d_in, const int* in_sizes, int n_in,
                              void* d_out, int out_size, void* d_ws, size_t ws_size,
                              hipStream_t stream) {
    (void)n_in; (void)out_size; (void)ws_size;
    const float* emb  = (const float*)d_in[0];
    const float* cls  = (const float*)d_in[1];
    const float* ln1g = (const float*)d_in[2];
    const float* ln1b = (const float*)d_in[3];
    const float* wq   = (const float*)d_in[4];
    const float* bq   = (const float*)d_in[5];
    const float* wk   = (const float*)d_in[6];
    const float* bk   = (const float*)d_in[7];
    const float* wv   = (const float*)d_in[8];
    const float* bv   = (const float*)d_in[9];
    const float* wo   = (const float*)d_in[10];
    const float* bo   = (const float*)d_in[11];
    const float* ln2g = (const float*)d_in[12];
    const float* ln2b = (const float*)d_in[13];
    const float* w1   = (const float*)d_in[14];
    const float* b1   = (const float*)d_in[15];
    const float* w2   = (const float*)d_in[16];
    const float* b2   = (const float*)d_in[17];
    const float* olng = (const float*)d_in[18];
    const float* olnb = (const float*)d_in[19];
    const int*   dvec = (const int*)d_in[20];
    float* out = (float*)d_out;
    u16*   ws  = (u16*)d_ws;

    hipLaunchKernelGGL(prep_weights, dim3(1536), dim3(256), 0, stream,
                       wq, wk, wv, wo, w1, w2, ws);

    const int N = in_sizes[0] / (SEQ * EDIM);   // B*T = 4096
    hipLaunchKernelGGL(row_former, dim3(N), dim3(256), 0, stream,
                       emb, cls, ln1g, ln1b, bq, bk, bv, bo,
                       ln2g, ln2b, b1, b2, olng, olnb, dvec, ws, out);
}